// Round 13
// baseline (288.099 us; speedup 1.0000x reference)
//
#include <hip/hip_runtime.h>
#include <hip/hip_cooperative_groups.h>

namespace cg = cooperative_groups;

#define NODES 4096
#define NDIM  512
#define HID   4096

typedef __attribute__((ext_vector_type(8))) short bf16x8;
typedef __attribute__((ext_vector_type(4))) float f32x4;

__device__ __forceinline__ float b2f(short v) {
  union { unsigned int u; float f; } c;
  c.u = ((unsigned int)(unsigned short)v) << 16;
  return c.f;
}
__device__ __forceinline__ short f2b(float f) {
  union { float f; unsigned int u; } c; c.f = f;
  unsigned int r = c.u + 0x7fffu + ((c.u >> 16) & 1u);  // round-nearest-even
  return (short)(r >> 16);
}

// Single cooperative kernel: 256 blocks x 512 threads, 128 KB dynamic LDS.
// S0 prep | S1 256^2 4-phase MFMA GEMM (R12-proven) | S2 svec+=W2^T a |
// S3 t=W2 s + beta | S4 kv=A t + beta | S5 uacc+=W3^T kv | S6 out.
__global__ __launch_bounds__(512, 2) void k_mega(
    const float* __restrict__ x,  const float* __restrict__ W1,
    const float* __restrict__ W2, const float* __restrict__ W3,
    const float* __restrict__ b1, const float* __restrict__ b2,
    const float* __restrict__ b3, const float* __restrict__ W4,
    const float* __restrict__ b4,
    short* __restrict__ xb, short* __restrict__ w1t, short* __restrict__ Abf,
    float* __restrict__ aacc, float* __restrict__ svec, float* __restrict__ tvec,
    float* __restrict__ kvv, float* __restrict__ uacc, float* __restrict__ beta,
    float* __restrict__ out) {
  extern __shared__ char smem[];        // 131072 B
  __shared__ float csum[256];
  __shared__ float red[8];
  cg::grid_group grid = cg::this_grid();

  const int tid  = threadIdx.x;
  const int lane = tid & 63;
  const int wid  = tid >> 6;            // 0..7
  const int gtid = blockIdx.x * 512 + tid;

  // ================= S0: prep =================
  {
    // cast x -> bf16 (2M elems, 4 float4 per thread)
    for (int i = gtid; i < NODES * NDIM / 4; i += 131072) {
      float4 v = *(const float4*)(x + (size_t)i * 4);
      short4 o;
      o.x = f2b(v.x); o.y = f2b(v.y); o.z = f2b(v.z); o.w = f2b(v.w);
      *(short4*)(xb + (size_t)i * 4) = o;
    }
    // transpose W1 [512][4096] -> w1t [4096][512] bf16; one 32x32 tile per wave
    float* tl = (float*)smem + wid * (32 * 34);  // 8 waves * 4352 B
    int t = blockIdx.x * 8 + wid;                // 2048 tiles
    int n0 = (t & 127) * 32, k0 = (t >> 7) * 32;
    int tx = lane & 31, ty = lane >> 5;
    #pragma unroll
    for (int j = 0; j < 16; ++j) {
      int kk = ty + j * 2;
      tl[kk * 34 + tx] = W1[(size_t)(k0 + kk) * HID + n0 + tx];
    }
    __syncthreads();
    #pragma unroll
    for (int j = 0; j < 16; ++j) {
      int nn = ty + j * 2;
      w1t[(size_t)(n0 + nn) * NDIM + k0 + tx] = f2b(tl[tx * 34 + nn]);
    }
    // init accumulators
    if (gtid < HID) {
      aacc[gtid] = 0.f;
      svec[gtid] = (float)NODES * b2[gtid];
      uacc[gtid] = b3[gtid];
    }
  }
  grid.sync();

  // ================= S1: A = relu(x@W1+b1), colsum -> aacc =================
  {
    const int wr = wid >> 2;            // 0..1  (M)
    const int wc = wid & 3;             // 0..3  (N)
    int bswz = (blockIdx.x & 7) * 32 + (blockIdx.x >> 3);
    const int brow = (bswz >> 4) * 256, bcol = (bswz & 15) * 256;

    f32x4 acc[8][4];
    #pragma unroll
    for (int i = 0; i < 8; ++i)
      #pragma unroll
      for (int j = 0; j < 4; ++j)
        acc[i][j] = (f32x4){0.f, 0.f, 0.f, 0.f};

    if (tid < 256) csum[tid] = 0.f;

    const int fr  = lane & 15;
    const int fko = ((lane >> 4) ^ ((lane >> 1) & 3)) * 8;  // swizzled granule

    const int off0 = tid * 16;
    const int row0 = off0 >> 6;
    const int gs   = (off0 >> 4) & 3;
    const int ce0  = (gs ^ ((row0 >> 1) & 3)) * 8;
    const short* gA0 = xb  + (size_t)(brow + row0) * NDIM + ce0;
    const short* gA1 = xb  + (size_t)(brow + row0 + 128) * NDIM + ce0;
    const short* gB0 = w1t + (size_t)(bcol + row0) * NDIM + ce0;
    const short* gB1 = w1t + (size_t)(bcol + row0 + 128) * NDIM + ce0;

#define GLOAD(src, dst) __builtin_amdgcn_global_load_lds( \
    (const __attribute__((address_space(1))) void*)(src), \
    (__attribute__((address_space(3))) void*)(dst), 16, 0, 0)

#define STAGE_HALF(buf, tile_, kh) do { \
    char* bA_ = smem + (buf) * 32768 + (kh) * 16384; \
    char* bB_ = smem + 65536 + (buf) * 32768 + (kh) * 16384; \
    int ks_ = (tile_) * 64 + (kh) * 32; \
    GLOAD(gA0 + ks_, bA_ + off0); \
    GLOAD(gA1 + ks_, bA_ + off0 + 8192); \
    GLOAD(gB0 + ks_, bB_ + off0); \
    GLOAD(gB1 + ks_, bB_ + off0 + 8192); \
  } while (0)

#define DS_BFR(buf, kh) do { \
    const short* Bb_ = (const short*)(smem + 65536 + (buf) * 32768 + (kh) * 16384); \
    _Pragma("unroll") \
    for (int ni = 0; ni < 4; ++ni) \
      bfr[ni] = *(const bf16x8*)(Bb_ + (wc * 64 + ni * 16 + fr) * 32 + fko); \
  } while (0)

#define DS_AF(buf, kh, mh) do { \
    const short* Ab_ = (const short*)(smem + (buf) * 32768 + (kh) * 16384); \
    _Pragma("unroll") \
    for (int mi = 0; mi < 4; ++mi) \
      af[mi] = *(const bf16x8*)(Ab_ + (wr * 128 + ((mh) * 4 + mi) * 16 + fr) * 32 + fko); \
  } while (0)

#define MFMA16(mh) do { \
    __builtin_amdgcn_s_setprio(1); \
    _Pragma("unroll") \
    for (int mi = 0; mi < 4; ++mi) \
      _Pragma("unroll") \
      for (int ni = 0; ni < 4; ++ni) \
        acc[(mh) * 4 + mi][ni] = __builtin_amdgcn_mfma_f32_16x16x32_bf16( \
            bfr[ni], af[mi], acc[(mh) * 4 + mi][ni], 0, 0, 0); \
    __builtin_amdgcn_s_setprio(0); \
  } while (0)

#define BAR() __builtin_amdgcn_s_barrier()
#define LGKM0() asm volatile("s_waitcnt lgkmcnt(0)" ::: "memory")
#define WCNT(s) asm volatile("s_waitcnt " s ::: "memory")

#define ITER(kk, DO_S0, DO_S2, V1, V3) do { \
    int b_ = (kk) & 1; \
    bf16x8 af[4], bfr[4]; \
    if (DO_S0) STAGE_HALF(((kk) + 1) & 1, (kk) + 1, 1); \
    DS_BFR(b_, 0); DS_AF(b_, 0, 0); \
    BAR(); LGKM0(); \
    MFMA16(0); \
    BAR(); \
    DS_AF(b_, 0, 1); \
    BAR(); LGKM0(); \
    MFMA16(1); \
    WCNT(V1); BAR(); \
    if (DO_S2) STAGE_HALF(b_, (kk) + 2, 0); \
    DS_BFR(b_, 1); DS_AF(b_, 1, 0); \
    BAR(); LGKM0(); \
    MFMA16(0); \
    BAR(); \
    DS_AF(b_, 1, 1); \
    BAR(); LGKM0(); \
    MFMA16(1); \
    WCNT(V3); BAR(); \
  } while (0)

    STAGE_HALF(0, 0, 0);
    STAGE_HALF(0, 0, 1);
    STAGE_HALF(1, 1, 0);
    WCNT("vmcnt(8)");
    BAR();

    #pragma unroll 1
    for (int kt = 0; kt < 6; ++kt)
      ITER(kt, true, true, "vmcnt(8)", "vmcnt(8)");
    ITER(6, true, false, "vmcnt(8)", "vmcnt(4)");
    ITER(7, false, false, "vmcnt(0)", "vmcnt(0)");

    // epilogue: bias + relu + csum; padded-LDS repack -> coalesced stores
    const int cr = lane & 15;
    const int cg = (lane >> 4) * 4;
    float4 bias4[4];
    #pragma unroll
    for (int ni = 0; ni < 4; ++ni)
      bias4[ni] = *(const float4*)(b1 + bcol + wc * 64 + ni * 16 + cg);

    float cl[4][4];
    #pragma unroll
    for (int ni = 0; ni < 4; ++ni)
      #pragma unroll
      for (int r = 0; r < 4; ++r)
        cl[ni][r] = 0.f;

    short* pk = (short*)smem;           // [128][264] shorts
    #pragma unroll 1
    for (int half = 0; half < 2; ++half) {
      __syncthreads();
      if (wr == half) {
        #pragma unroll
        for (int mi = 0; mi < 8; ++mi) {
          int lrow = mi * 16 + cr;
          #pragma unroll
          for (int ni = 0; ni < 4; ++ni) {
            float v0 = fmaxf(acc[mi][ni][0] + bias4[ni].x, 0.f);
            float v1 = fmaxf(acc[mi][ni][1] + bias4[ni].y, 0.f);
            float v2 = fmaxf(acc[mi][ni][2] + bias4[ni].z, 0.f);
            float v3 = fmaxf(acc[mi][ni][3] + bias4[ni].w, 0.f);
            cl[ni][0] += v0; cl[ni][1] += v1; cl[ni][2] += v2; cl[ni][3] += v3;
            short4 o;
            o.x = f2b(v0); o.y = f2b(v1); o.z = f2b(v2); o.w = f2b(v3);
            *(short4*)(pk + lrow * 264 + wc * 64 + ni * 16 + cg) = o;
          }
        }
      }
      __syncthreads();
      #pragma unroll
      for (int i = 0; i < 8; ++i) {
        int c = tid + i * 512;
        int row = c >> 5, ch = c & 31;
        bf16x8 vv = *(const bf16x8*)(pk + row * 264 + ch * 8);
        *(bf16x8*)(Abf + (size_t)(brow + half * 128 + row) * HID + bcol + ch * 8) = vv;
      }
    }

    #pragma unroll
    for (int ni = 0; ni < 4; ++ni)
      #pragma unroll
      for (int r = 0; r < 4; ++r) {
        #pragma unroll
        for (int m = 1; m < 16; m <<= 1)
          cl[ni][r] += __shfl_xor(cl[ni][r], m);
      }
    if (cr == 0) {
      #pragma unroll
      for (int ni = 0; ni < 4; ++ni)
        #pragma unroll
        for (int r = 0; r < 4; ++r)
          atomicAdd(&csum[wc * 64 + ni * 16 + cg + r], cl[ni][r]);
    }
    __syncthreads();
    if (tid < 256) atomicAdd(&aacc[bcol + tid], csum[tid]);
  }
  grid.sync();

  // ================= S2: svec += W2^T aacc =================
  {
    int vb = blockIdx.x * 2 + (tid >> 8);   // 0..511 virtual 256-thread blocks
    int vt = tid & 255;
    int col = (vb & 3) * 1024 + vt * 4;
    int r0  = (vb >> 2) * 32;
    float4 a4 = {0.f, 0.f, 0.f, 0.f};
    const float* base = W2 + (size_t)r0 * HID + col;
    #pragma unroll 16
    for (int i = 0; i < 32; ++i) {
      float vi = aacc[r0 + i];
      float4 wv = *(const float4*)(base + (size_t)i * HID);
      a4.x += vi * wv.x; a4.y += vi * wv.y;
      a4.z += vi * wv.z; a4.w += vi * wv.w;
    }
    atomicAdd(&svec[col + 0], a4.x);
    atomicAdd(&svec[col + 1], a4.y);
    atomicAdd(&svec[col + 2], a4.z);
    atomicAdd(&svec[col + 3], a4.w);
  }
  grid.sync();

  // ================= S3: tvec = W2 . svec ; beta = b2 . svec =================
  {
    int wg = blockIdx.x * 8 + wid;          // 0..2047, 2 rows each
    const float* base0 = W2 + (size_t)(wg * 2) * HID;
    const float* base1 = base0 + HID;
    float p0 = 0.f, p1 = 0.f;
    #pragma unroll 4
    for (int j = lane * 4; j < HID; j += 256) {
      float4 s4 = *(const float4*)(svec + j);
      float4 w0 = *(const float4*)(base0 + j);
      float4 w1v = *(const float4*)(base1 + j);
      p0 += w0.x * s4.x + w0.y * s4.y + w0.z * s4.z + w0.w * s4.w;
      p1 += w1v.x * s4.x + w1v.y * s4.y + w1v.z * s4.z + w1v.w * s4.w;
    }
    #pragma unroll
    for (int o = 32; o > 0; o >>= 1) {
      p0 += __shfl_down(p0, o);
      p1 += __shfl_down(p1, o);
    }
    if (lane == 0) {
      tvec[wg * 2]     = p0;
      tvec[wg * 2 + 1] = p1;
    }
    if (wg == 0) {                          // beta by wave 0 of block 0
      float p = 0.f;
      for (int j = lane; j < HID; j += 64) p += b2[j] * svec[j];
      #pragma unroll
      for (int o = 32; o > 0; o >>= 1) p += __shfl_down(p, o);
      if (lane == 0) beta[0] = p;
    }
  }
  grid.sync();

  // ================= S4: kvv = Abf . tvec + beta =================
  {
    int wg = blockIdx.x * 8 + wid;          // 2 rows each
    const short* base0 = Abf + (size_t)(wg * 2) * HID;
    const short* base1 = base0 + HID;
    float p0 = 0.f, p1 = 0.f;
    #pragma unroll
    for (int j = lane * 8; j < HID; j += 512) {
      bf16x8 a0 = *(const bf16x8*)(base0 + j);
      bf16x8 a1 = *(const bf16x8*)(base1 + j);
      float4 t0 = *(const float4*)(tvec + j);
      float4 t1 = *(const float4*)(tvec + j + 4);
      p0 += b2f(a0[0]) * t0.x + b2f(a0[1]) * t0.y + b2f(a0[2]) * t0.z + b2f(a0[3]) * t0.w
          + b2f(a0[4]) * t1.x + b2f(a0[5]) * t1.y + b2f(a0[6]) * t1.z + b2f(a0[7]) * t1.w;
      p1 += b2f(a1[0]) * t0.x + b2f(a1[1]) * t0.y + b2f(a1[2]) * t0.z + b2f(a1[3]) * t0.w
          + b2f(a1[4]) * t1.x + b2f(a1[5]) * t1.y + b2f(a1[6]) * t1.z + b2f(a1[7]) * t1.w;
    }
    #pragma unroll
    for (int o = 32; o > 0; o >>= 1) {
      p0 += __shfl_down(p0, o);
      p1 += __shfl_down(p1, o);
    }
    if (lane == 0) {
      float bb = beta[0];
      kvv[wg * 2]     = p0 + bb;
      kvv[wg * 2 + 1] = p1 + bb;
    }
  }
  grid.sync();

  // ================= S5: uacc += W3^T kvv =================
  {
    int vb = blockIdx.x * 2 + (tid >> 8);
    int vt = tid & 255;
    int col = (vb & 3) * 1024 + vt * 4;
    int r0  = (vb >> 2) * 32;
    float4 a4 = {0.f, 0.f, 0.f, 0.f};
    const float* base = W3 + (size_t)r0 * HID + col;
    #pragma unroll 16
    for (int i = 0; i < 32; ++i) {
      float vi = kvv[r0 + i];
      float4 wv = *(const float4*)(base + (size_t)i * HID);
      a4.x += vi * wv.x; a4.y += vi * wv.y;
      a4.z += vi * wv.z; a4.w += vi * wv.w;
    }
    atomicAdd(&uacc[col + 0], a4.x);
    atomicAdd(&uacc[col + 1], a4.y);
    atomicAdd(&uacc[col + 2], a4.z);
    atomicAdd(&uacc[col + 3], a4.w);
  }
  grid.sync();

  // ================= S6: out = relu(uacc) . W4 + b4 =================
  if (blockIdx.x == 0) {
    float p = 0.f;
    for (int j = tid; j < HID; j += 512) {
      float u = uacc[j];
      u = u > 0.f ? u : 0.f;
      p += u * W4[j];
    }
    #pragma unroll
    for (int o = 32; o > 0; o >>= 1) p += __shfl_down(p, o);
    if (lane == 0) red[wid] = p;
    __syncthreads();
    if (tid == 0) {
      float s = 0.f;
      #pragma unroll
      for (int i = 0; i < 8; ++i) s += red[i];
      out[0] = s + b4[0];
    }
  }
}

extern "C" void kernel_launch(void* const* d_in, const int* in_sizes, int n_in,
                              void* d_out, int out_size, void* d_ws, size_t ws_size,
                              hipStream_t stream) {
  const float* x  = (const float*)d_in[0];
  // d_in[1] = edge_index (dead in the reference)
  const float* W1 = (const float*)d_in[2];
  const float* b1 = (const float*)d_in[3];
  const float* W2 = (const float*)d_in[4];
  const float* b2 = (const float*)d_in[5];
  const float* W3 = (const float*)d_in[6];
  const float* b3 = (const float*)d_in[7];
  const float* W4 = (const float*)d_in[8];
  const float* b4 = (const float*)d_in[9];
  float* out = (float*)d_out;

  char* ws = (char*)d_ws;
  short* Abf  = (short*)(ws);                 // 32 MB
  short* xb   = (short*)(ws + 33554432);      // 4 MB
  short* w1t  = (short*)(ws + 37748736);      // 4 MB
  float* aacc = (float*)(ws + 41943040);
  float* svec = (float*)(ws + 41959424);
  float* tvec = (float*)(ws + 41975808);
  float* kvv  = (float*)(ws + 41992192);
  float* uacc = (float*)(ws + 42008576);
  float* beta = (float*)(ws + 42024960);

  void* args[] = {
    (void*)&x, (void*)&W1, (void*)&W2, (void*)&W3, (void*)&b1, (void*)&b2,
    (void*)&b3, (void*)&W4, (void*)&b4, (void*)&xb, (void*)&w1t, (void*)&Abf,
    (void*)&aacc, (void*)&svec, (void*)&tvec, (void*)&kvv, (void*)&uacc,
    (void*)&beta, (void*)&out
  };
  hipLaunchCooperativeKernel((const void*)k_mega, dim3(256), dim3(512),
                             args, 131072, stream);
}

// Round 14
// 108.310 us; speedup vs baseline: 2.6599x; 2.6599x over previous
//
#include <hip/hip_runtime.h>

#define NODES 4096
#define NDIM  512
#define HID   4096

typedef __attribute__((ext_vector_type(8))) short bf16x8;
typedef __attribute__((ext_vector_type(4))) float f32x4;

__device__ __forceinline__ float b2f(short v) {
  union { unsigned int u; float f; } c;
  c.u = ((unsigned int)(unsigned short)v) << 16;
  return c.f;
}
__device__ __forceinline__ short f2b(float f) {
  union { float f; unsigned int u; } c; c.f = f;
  unsigned int r = c.u + 0x7fffu + ((c.u >> 16) & 1u);  // round-nearest-even
  return (short)(r >> 16);
}

// ---- K0: fused prep: cast x->bf16 | transpose+cast W1 | init accumulators ----
__global__ __launch_bounds__(256) void k_prep(const float* __restrict__ x,
                                              const float* __restrict__ W1,
                                              const float* __restrict__ b2,
                                              const float* __restrict__ b3,
                                              short* __restrict__ xb,
                                              short* __restrict__ w1t,
                                              float* __restrict__ aacc,
                                              float* __restrict__ svec,
                                              float* __restrict__ uacc) {
  __shared__ float tile[32][33];
  int b = blockIdx.x;
  if (b < 2048) {                       // cast x (4096x512 fp32 -> bf16)
    int i = (b * 256 + threadIdx.x) * 4;
    float4 v = *(const float4*)(x + i);
    short4 o;
    o.x = f2b(v.x); o.y = f2b(v.y); o.z = f2b(v.z); o.w = f2b(v.w);
    *(short4*)(xb + i) = o;
  } else if (b < 4096) {                // transpose W1 [512][4096] -> [4096][512] bf16
    int t = b - 2048;
    int n0 = (t & 127) * 32;
    int k0 = (t >> 7) * 32;
    int tx = threadIdx.x & 31, ty = threadIdx.x >> 5;
    #pragma unroll
    for (int j = 0; j < 4; ++j) {
      int kk = ty + j * 8;
      tile[kk][tx] = W1[(size_t)(k0 + kk) * HID + n0 + tx];
    }
    __syncthreads();
    #pragma unroll
    for (int j = 0; j < 4; ++j) {
      int nn = ty + j * 8;
      w1t[(size_t)(n0 + nn) * NDIM + k0 + tx] = f2b(tile[tx][nn]);
    }
  } else {                              // init: a=0, s=N*b2, u=b3
    int j = (b - 4096) * 256 + threadIdx.x;
    aacc[j] = 0.0f;
    svec[j] = (float)NODES * b2[j];
    uacc[j] = b3[j];
  }
}

// ---- K1: A = relu(x @ W1 + b1) (bf16 MFMA), fused column sums ----
// 256x256 tile, BK=64, 8 waves (2M x 4N, 128x64/wave). 4-phase fine-interleave
// per K-tile: {ds_read || half-tile stage -> barrier -> lgkmcnt(0) -> 16 MFMA
// -> barrier}, counted vmcnt(8). Granule swizzle + padded-LDS repack epilogue.
__global__ __launch_bounds__(512, 2) void k_gemm1(const short* __restrict__ xb,
                                                  const short* __restrict__ w1t,
                                                  const float* __restrict__ b1,
                                                  short* __restrict__ Aout,
                                                  float* __restrict__ colsum) {
  extern __shared__ char smem[];        // 131072 B:
                                        // A: buf*32768 + kh*16384   (0..65535)
                                        // B: 65536 + buf*32768 + kh*16384
  __shared__ float csum[256];

  const int tid  = threadIdx.x;
  const int lane = tid & 63;
  const int wid  = tid >> 6;            // 0..7
  const int wr   = wid >> 2;            // 0..1  (M)
  const int wc   = wid & 3;             // 0..3  (N)

  // XCD-aware swizzle (256 blocks, %8==0 -> simple bijective form)
  int bswz = (blockIdx.x & 7) * 32 + (blockIdx.x >> 3);
  const int brow = (bswz >> 4) * 256, bcol = (bswz & 15) * 256;

  f32x4 acc[8][4];
  #pragma unroll
  for (int i = 0; i < 8; ++i)
    #pragma unroll
    for (int j = 0; j < 4; ++j)
      acc[i][j] = (f32x4){0.f, 0.f, 0.f, 0.f};

  if (tid < 256) csum[tid] = 0.f;

  const int fr = lane & 15;
  // swizzled fragment granule: logical g = lane>>4, row-phase = (fr>>1)&3
  const int fko = ((lane >> 4) ^ ((lane >> 1) & 3)) * 8;  // shorts, in [0,32)

  // staging: each kh-subtile is [256][32] shorts (64-B rows), LDS dest linear.
  // Source granule pre-swizzled with the SAME involution: g' = g ^ ((row>>1)&3).
  const int off0 = tid * 16;
  const int row0 = off0 >> 6;
  const int gs   = (off0 >> 4) & 3;                     // linear granule
  const int ce0  = (gs ^ ((row0 >> 1) & 3)) * 8;        // swizzled source offset
  const short* gA0 = xb  + (size_t)(brow + row0) * NDIM + ce0;
  const short* gA1 = xb  + (size_t)(brow + row0 + 128) * NDIM + ce0;
  const short* gB0 = w1t + (size_t)(bcol + row0) * NDIM + ce0;
  const short* gB1 = w1t + (size_t)(bcol + row0 + 128) * NDIM + ce0;

#define GLOAD(src, dst) __builtin_amdgcn_global_load_lds( \
    (const __attribute__((address_space(1))) void*)(src), \
    (__attribute__((address_space(3))) void*)(dst), 16, 0, 0)

#define STAGE_HALF(buf, tile_, kh) do { \
    char* bA_ = smem + (buf) * 32768 + (kh) * 16384; \
    char* bB_ = smem + 65536 + (buf) * 32768 + (kh) * 16384; \
    int ks_ = (tile_) * 64 + (kh) * 32; \
    GLOAD(gA0 + ks_, bA_ + off0); \
    GLOAD(gA1 + ks_, bA_ + off0 + 8192); \
    GLOAD(gB0 + ks_, bB_ + off0); \
    GLOAD(gB1 + ks_, bB_ + off0 + 8192); \
  } while (0)

#define DS_BFR(buf, kh) do { \
    const short* Bb_ = (const short*)(smem + 65536 + (buf) * 32768 + (kh) * 16384); \
    _Pragma("unroll") \
    for (int ni = 0; ni < 4; ++ni) \
      bfr[ni] = *(const bf16x8*)(Bb_ + (wc * 64 + ni * 16 + fr) * 32 + fko); \
  } while (0)

#define DS_AF(buf, kh, mh) do { \
    const short* Ab_ = (const short*)(smem + (buf) * 32768 + (kh) * 16384); \
    _Pragma("unroll") \
    for (int mi = 0; mi < 4; ++mi) \
      af[mi] = *(const bf16x8*)(Ab_ + (wr * 128 + ((mh) * 4 + mi) * 16 + fr) * 32 + fko); \
  } while (0)

  // swapped operands: acc[mi][ni] = C^T fragment
  // value(lane,reg) = C[row = mi*16+(lane&15)][col = ni*16+(lane>>4)*4+reg]
#define MFMA16(mh) do { \
    __builtin_amdgcn_s_setprio(1); \
    _Pragma("unroll") \
    for (int mi = 0; mi < 4; ++mi) \
      _Pragma("unroll") \
      for (int ni = 0; ni < 4; ++ni) \
        acc[(mh) * 4 + mi][ni] = __builtin_amdgcn_mfma_f32_16x16x32_bf16( \
            bfr[ni], af[mi], acc[(mh) * 4 + mi][ni], 0, 0, 0); \
    __builtin_amdgcn_s_setprio(0); \
  } while (0)

#define BAR() __builtin_amdgcn_s_barrier()
#define LGKM0() asm volatile("s_waitcnt lgkmcnt(0)" ::: "memory")
#define WCNT(s) asm volatile("s_waitcnt " s ::: "memory")

#define ITER(kk, DO_S0, DO_S2, V1, V3) do { \
    int b_ = (kk) & 1; \
    bf16x8 af[4], bfr[4]; \
    if (DO_S0) STAGE_HALF(((kk) + 1) & 1, (kk) + 1, 1); \
    DS_BFR(b_, 0); DS_AF(b_, 0, 0); \
    BAR(); LGKM0(); \
    MFMA16(0); \
    BAR(); \
    DS_AF(b_, 0, 1); \
    BAR(); LGKM0(); \
    MFMA16(1); \
    WCNT(V1); BAR(); \
    if (DO_S2) STAGE_HALF(b_, (kk) + 2, 0); \
    DS_BFR(b_, 1); DS_AF(b_, 1, 0); \
    BAR(); LGKM0(); \
    MFMA16(0); \
    BAR(); \
    DS_AF(b_, 1, 1); \
    BAR(); LGKM0(); \
    MFMA16(1); \
    WCNT(V3); BAR(); \
  } while (0)

  // prologue: kh0(0), kh1(0), kh0(1) in flight (12); retire kh0(0)
  STAGE_HALF(0, 0, 0);
  STAGE_HALF(0, 0, 1);
  STAGE_HALF(1, 1, 0);
  WCNT("vmcnt(8)");
  BAR();

  #pragma unroll 1
  for (int kt = 0; kt < 6; ++kt)
    ITER(kt, true, true, "vmcnt(8)", "vmcnt(8)");
  ITER(6, true, false, "vmcnt(8)", "vmcnt(4)");
  ITER(7, false, false, "vmcnt(0)", "vmcnt(0)");

  // ---- epilogue: bias + relu + csum; padded-LDS repack -> coalesced stores
  const int cr = lane & 15;            // output row within 16-frag
  const int cg = (lane >> 4) * 4;      // output col base within 16-frag
  float4 bias4[4];
  #pragma unroll
  for (int ni = 0; ni < 4; ++ni)
    bias4[ni] = *(const float4*)(b1 + bcol + wc * 64 + ni * 16 + cg);

  float cl[4][4];
  #pragma unroll
  for (int ni = 0; ni < 4; ++ni)
    #pragma unroll
    for (int r = 0; r < 4; ++r)
      cl[ni][r] = 0.f;

  short* pk = (short*)smem;            // [128][264] shorts = 67584 B (fits 128 KB)
  #pragma unroll 1
  for (int half = 0; half < 2; ++half) {
    __syncthreads();                   // K-loop reads / prev half's stores done
    if (wr == half) {                  // owning waves write their 128 rows
      #pragma unroll
      for (int mi = 0; mi < 8; ++mi) {
        int lrow = mi * 16 + cr;       // 0..127 within half
        #pragma unroll
        for (int ni = 0; ni < 4; ++ni) {
          float v0 = fmaxf(acc[mi][ni][0] + bias4[ni].x, 0.f);
          float v1 = fmaxf(acc[mi][ni][1] + bias4[ni].y, 0.f);
          float v2 = fmaxf(acc[mi][ni][2] + bias4[ni].z, 0.f);
          float v3 = fmaxf(acc[mi][ni][3] + bias4[ni].w, 0.f);
          cl[ni][0] += v0; cl[ni][1] += v1; cl[ni][2] += v2; cl[ni][3] += v3;
          short4 o;
          o.x = f2b(v0); o.y = f2b(v1); o.z = f2b(v2); o.w = f2b(v3);
          *(short4*)(pk + lrow * 264 + wc * 64 + ni * 16 + cg) = o;
        }
      }
    }
    __syncthreads();
    // all 8 waves store 64 KB: 128 rows x 512 B, fully coalesced b128
    #pragma unroll
    for (int i = 0; i < 8; ++i) {
      int c = tid + i * 512;           // 0..4095 chunks of 16 B
      int row = c >> 5, ch = c & 31;
      bf16x8 vv = *(const bf16x8*)(pk + row * 264 + ch * 8);
      *(bf16x8*)(Aout + (size_t)(brow + half * 128 + row) * HID + bcol + ch * 8) = vv;
    }
  }

  // column sums: reduce over the 16 rows (lanes sharing lane>>4)
  #pragma unroll
  for (int ni = 0; ni < 4; ++ni)
    #pragma unroll
    for (int r = 0; r < 4; ++r) {
      #pragma unroll
      for (int m = 1; m < 16; m <<= 1)
        cl[ni][r] += __shfl_xor(cl[ni][r], m);
    }
  if (cr == 0) {                       // 4 lanes/wave; wr=0/1 -> 2-way contention
    #pragma unroll
    for (int ni = 0; ni < 4; ++ni)
      #pragma unroll
      for (int r = 0; r < 4; ++r)
        atomicAdd(&csum[wc * 64 + ni * 16 + cg + r], cl[ni][r]);
  }
  __syncthreads();
  if (tid < 256) atomicAdd(&colsum[bcol + tid], csum[tid]);
}

// ---- K2/K5: vout[col] += sum_i vin[i] * W[i][col]  (W: [4096][4096] fp32) ----
__global__ __launch_bounds__(256) void k_gemv_at(const float* __restrict__ W,
                                                 const float* __restrict__ vin,
                                                 float* __restrict__ vout) {
  const int col = blockIdx.x * 1024 + threadIdx.x * 4;
  const int r0  = blockIdx.y * 64;
  float4 accv = {0.f, 0.f, 0.f, 0.f};
  const float* base = W + (size_t)r0 * HID + col;
  #pragma unroll 16
  for (int i = 0; i < 64; ++i) {
    float vi = vin[r0 + i];
    float4 wv = *(const float4*)(base + (size_t)i * HID);
    accv.x += vi * wv.x; accv.y += vi * wv.y;
    accv.z += vi * wv.z; accv.w += vi * wv.w;
  }
  atomicAdd(&vout[col + 0], accv.x);
  atomicAdd(&vout[col + 1], accv.y);
  atomicAdd(&vout[col + 2], accv.z);
  atomicAdd(&vout[col + 3], accv.w);
}

// ---- K3: t = W2 . s (2 rows/wave, dual accumulators); block 512 does beta ----
__global__ __launch_bounds__(256) void k_gemv_row(const float* __restrict__ W,
                                                  const float* __restrict__ vin,
                                                  const float* __restrict__ b2,
                                                  float* __restrict__ vout,
                                                  float* __restrict__ beta) {
  int w = threadIdx.x >> 6, lane = threadIdx.x & 63;
  if (blockIdx.x == HID / 8) {           // beta block (wave 0 only)
    if (w == 0) {
      float p = 0.f;
      for (int j = lane; j < HID; j += 64) p += b2[j] * vin[j];
      #pragma unroll
      for (int o = 32; o > 0; o >>= 1) p += __shfl_down(p, o);
      if (lane == 0) beta[0] = p;
    }
    return;
  }
  int wg = blockIdx.x * 4 + w;           // 2 rows per wave
  const float* base0 = W + (size_t)(wg * 2) * HID;
  const float* base1 = base0 + HID;
  float p0 = 0.f, p1 = 0.f;
  #pragma unroll 4
  for (int j = lane * 4; j < HID; j += 256) {
    float4 s4 = *(const float4*)(vin + j);
    float4 w0 = *(const float4*)(base0 + j);
    float4 w1v = *(const float4*)(base1 + j);
    p0 += w0.x * s4.x + w0.y * s4.y + w0.z * s4.z + w0.w * s4.w;
    p1 += w1v.x * s4.x + w1v.y * s4.y + w1v.z * s4.z + w1v.w * s4.w;
  }
  #pragma unroll
  for (int o = 32; o > 0; o >>= 1) {
    p0 += __shfl_down(p0, o);
    p1 += __shfl_down(p1, o);
  }
  if (lane == 0) {
    vout[wg * 2]     = p0;
    vout[wg * 2 + 1] = p1;
  }
}

// ---- K4: kv = A . t + beta (A bf16; 2 rows/wave, dual accumulators) ----
__global__ __launch_bounds__(256) void k_kv(const short* __restrict__ A,
                                            const float* __restrict__ t,
                                            const float* __restrict__ beta,
                                            float* __restrict__ kv) {
  int w = threadIdx.x >> 6, lane = threadIdx.x & 63;
  int wg = blockIdx.x * 4 + w;           // 2 rows per wave
  const short* base0 = A + (size_t)(wg * 2) * HID;
  const short* base1 = base0 + HID;
  float p0 = 0.f, p1 = 0.f;
  #pragma unroll
  for (int j = lane * 8; j < HID; j += 512) {
    bf16x8 a0 = *(const bf16x8*)(base0 + j);
    bf16x8 a1 = *(const bf16x8*)(base1 + j);
    float4 t0 = *(const float4*)(t + j);
    float4 t1 = *(const float4*)(t + j + 4);
    p0 += b2f(a0[0]) * t0.x + b2f(a0[1]) * t0.y + b2f(a0[2]) * t0.z + b2f(a0[3]) * t0.w
        + b2f(a0[4]) * t1.x + b2f(a0[5]) * t1.y + b2f(a0[6]) * t1.z + b2f(a0[7]) * t1.w;
    p1 += b2f(a1[0]) * t0.x + b2f(a1[1]) * t0.y + b2f(a1[2]) * t0.z + b2f(a1[3]) * t0.w
        + b2f(a1[4]) * t1.x + b2f(a1[5]) * t1.y + b2f(a1[6]) * t1.z + b2f(a1[7]) * t1.w;
  }
  #pragma unroll
  for (int o = 32; o > 0; o >>= 1) {
    p0 += __shfl_down(p0, o);
    p1 += __shfl_down(p1, o);
  }
  if (lane == 0) {
    float bb = beta[0];
    kv[wg * 2]     = p0 + bb;
    kv[wg * 2 + 1] = p1 + bb;
  }
}

// ---- K6: out = relu(uacc) . W4 + b4 ----
__global__ __launch_bounds__(256) void k_final(const float* __restrict__ uacc,
                                               const float* __restrict__ W4,
                                               const float* __restrict__ b4,
                                               float* __restrict__ out) {
  __shared__ float red[4];
  float p = 0.f;
  for (int j = threadIdx.x; j < HID; j += 256) {
    float uv = uacc[j];
    uv = uv > 0.f ? uv : 0.f;
    p += uv * W4[j];
  }
  #pragma unroll
  for (int o = 32; o > 0; o >>= 1) p += __shfl_down(p, o);
  int lane = threadIdx.x & 63, w = threadIdx.x >> 6;
  if (lane == 0) red[w] = p;
  __syncthreads();
  if (threadIdx.x == 0) out[0] = red[0] + red[1] + red[2] + red[3] + b4[0];
}

extern "C" void kernel_launch(void* const* d_in, const int* in_sizes, int n_in,
                              void* d_out, int out_size, void* d_ws, size_t ws_size,
                              hipStream_t stream) {
  const float* x  = (const float*)d_in[0];
  // d_in[1] = edge_index (dead in the reference)
  const float* W1 = (const float*)d_in[2];
  const float* b1 = (const float*)d_in[3];
  const float* W2 = (const float*)d_in[4];
  const float* b2 = (const float*)d_in[5];
  const float* W3 = (const float*)d_in[6];
  const float* b3 = (const float*)d_in[7];
  const float* W4 = (const float*)d_in[8];
  const float* b4 = (const float*)d_in[9];
  float* out = (float*)d_out;

  char* ws = (char*)d_ws;
  short* Abf  = (short*)(ws);                 // 32 MB
  short* xb   = (short*)(ws + 33554432);      // 4 MB
  short* w1t  = (short*)(ws + 37748736);      // 4 MB
  float* aacc = (float*)(ws + 41943040);
  float* svec = (float*)(ws + 41959424);
  float* tvec = (float*)(ws + 41975808);
  float* kvv  = (float*)(ws + 41992192);
  float* uacc = (float*)(ws + 42008576);
  float* beta = (float*)(ws + 42024960);

  k_prep    <<<dim3(4112),     dim3(256), 0, stream>>>(x, W1, b2, b3, xb, w1t, aacc, svec, uacc);
  k_gemm1   <<<dim3(256),      dim3(512), 131072, stream>>>(xb, w1t, b1, Abf, aacc);
  k_gemv_at <<<dim3(4, 64),    dim3(256), 0, stream>>>(W2, aacc, svec);
  k_gemv_row<<<dim3(513),      dim3(256), 0, stream>>>(W2, svec, b2, tvec, beta);
  k_kv      <<<dim3(512),      dim3(256), 0, stream>>>(Abf, tvec, beta, kvv);
  k_gemv_at <<<dim3(4, 64),    dim3(256), 0, stream>>>(W3, kvv, uacc);
  k_final   <<<dim3(1),        dim3(256), 0, stream>>>(uacc, W4, b4, out);
}

// Round 15
// 91.880 us; speedup vs baseline: 3.1356x; 1.1788x over previous
//
#include <hip/hip_runtime.h>

#define NODES 4096
#define NDIM  512
#define HID   4096

typedef __attribute__((ext_vector_type(8))) short bf16x8;
typedef __attribute__((ext_vector_type(4))) float f32x4;

__device__ __forceinline__ float b2f(short v) {
  union { unsigned int u; float f; } c;
  c.u = ((unsigned int)(unsigned short)v) << 16;
  return c.f;
}
__device__ __forceinline__ short f2b(float f) {
  union { float f; unsigned int u; } c; c.f = f;
  unsigned int r = c.u + 0x7fffu + ((c.u >> 16) & 1u);  // round-nearest-even
  return (short)(r >> 16);
}

// ---- K0: fused prep: cast x->bf16 (16B stores) | transpose W1 | init accs ----
__global__ __launch_bounds__(256) void k_prep(const float* __restrict__ x,
                                              const float* __restrict__ W1,
                                              const float* __restrict__ b2,
                                              const float* __restrict__ b3,
                                              short* __restrict__ xb,
                                              short* __restrict__ w1t,
                                              float* __restrict__ aacc,
                                              float* __restrict__ svec,
                                              float* __restrict__ uacc) {
  __shared__ float tile[32][33];
  int b = blockIdx.x;
  if (b < 1024) {                       // cast x (4096x512 fp32 -> bf16), 8/thread
    int i = (b * 256 + threadIdx.x) * 8;
    float4 v0 = *(const float4*)(x + i);
    float4 v1 = *(const float4*)(x + i + 4);
    bf16x8 o;
    o[0] = f2b(v0.x); o[1] = f2b(v0.y); o[2] = f2b(v0.z); o[3] = f2b(v0.w);
    o[4] = f2b(v1.x); o[5] = f2b(v1.y); o[6] = f2b(v1.z); o[7] = f2b(v1.w);
    *(bf16x8*)(xb + i) = o;
  } else if (b < 3072) {                // transpose W1 [512][4096] -> [4096][512] bf16
    int t = b - 1024;
    int n0 = (t & 127) * 32;
    int k0 = (t >> 7) * 32;
    int tx = threadIdx.x & 31, ty = threadIdx.x >> 5;
    #pragma unroll
    for (int j = 0; j < 4; ++j) {
      int kk = ty + j * 8;
      tile[kk][tx] = W1[(size_t)(k0 + kk) * HID + n0 + tx];
    }
    __syncthreads();
    #pragma unroll
    for (int j = 0; j < 4; ++j) {
      int nn = ty + j * 8;
      w1t[(size_t)(n0 + nn) * NDIM + k0 + tx] = f2b(tile[tx][nn]);
    }
  } else {                              // init: a=0, s=N*b2, u=b3
    int j = (b - 3072) * 256 + threadIdx.x;
    aacc[j] = 0.0f;
    svec[j] = (float)NODES * b2[j];
    uacc[j] = b3[j];
  }
}

// ---- K1: A = relu(x @ W1 + b1) (bf16 MFMA), fused column sums ----
// 256x256 tile, BK=64, 8 waves (2M x 4N, 128x64/wave). 4-phase fine-interleave
// per K-tile: {ds_read || half-tile stage -> barrier -> lgkmcnt(0) -> 16 MFMA
// -> barrier}, counted vmcnt(8). Granule swizzle + padded-LDS repack epilogue.
__global__ __launch_bounds__(512, 2) void k_gemm1(const short* __restrict__ xb,
                                                  const short* __restrict__ w1t,
                                                  const float* __restrict__ b1,
                                                  short* __restrict__ Aout,
                                                  float* __restrict__ colsum) {
  extern __shared__ char smem[];        // 131072 B:
                                        // A: buf*32768 + kh*16384   (0..65535)
                                        // B: 65536 + buf*32768 + kh*16384
  __shared__ float csum[256];

  const int tid  = threadIdx.x;
  const int lane = tid & 63;
  const int wid  = tid >> 6;            // 0..7
  const int wr   = wid >> 2;            // 0..1  (M)
  const int wc   = wid & 3;             // 0..3  (N)

  // XCD-aware swizzle (256 blocks, %8==0 -> simple bijective form)
  int bswz = (blockIdx.x & 7) * 32 + (blockIdx.x >> 3);
  const int brow = (bswz >> 4) * 256, bcol = (bswz & 15) * 256;

  f32x4 acc[8][4];
  #pragma unroll
  for (int i = 0; i < 8; ++i)
    #pragma unroll
    for (int j = 0; j < 4; ++j)
      acc[i][j] = (f32x4){0.f, 0.f, 0.f, 0.f};

  if (tid < 256) csum[tid] = 0.f;

  const int fr = lane & 15;
  // swizzled fragment granule: logical g = lane>>4, row-phase = (fr>>1)&3
  const int fko = ((lane >> 4) ^ ((lane >> 1) & 3)) * 8;  // shorts, in [0,32)

  // staging: each kh-subtile is [256][32] shorts (64-B rows), LDS dest linear.
  // Source granule pre-swizzled with the SAME involution: g' = g ^ ((row>>1)&3).
  const int off0 = tid * 16;
  const int row0 = off0 >> 6;
  const int gs   = (off0 >> 4) & 3;                     // linear granule
  const int ce0  = (gs ^ ((row0 >> 1) & 3)) * 8;        // swizzled source offset
  const short* gA0 = xb  + (size_t)(brow + row0) * NDIM + ce0;
  const short* gA1 = xb  + (size_t)(brow + row0 + 128) * NDIM + ce0;
  const short* gB0 = w1t + (size_t)(bcol + row0) * NDIM + ce0;
  const short* gB1 = w1t + (size_t)(bcol + row0 + 128) * NDIM + ce0;

#define GLOAD(src, dst) __builtin_amdgcn_global_load_lds( \
    (const __attribute__((address_space(1))) void*)(src), \
    (__attribute__((address_space(3))) void*)(dst), 16, 0, 0)

#define STAGE_HALF(buf, tile_, kh) do { \
    char* bA_ = smem + (buf) * 32768 + (kh) * 16384; \
    char* bB_ = smem + 65536 + (buf) * 32768 + (kh) * 16384; \
    int ks_ = (tile_) * 64 + (kh) * 32; \
    GLOAD(gA0 + ks_, bA_ + off0); \
    GLOAD(gA1 + ks_, bA_ + off0 + 8192); \
    GLOAD(gB0 + ks_, bB_ + off0); \
    GLOAD(gB1 + ks_, bB_ + off0 + 8192); \
  } while (0)

#define DS_BFR(buf, kh) do { \
    const short* Bb_ = (const short*)(smem + 65536 + (buf) * 32768 + (kh) * 16384); \
    _Pragma("unroll") \
    for (int ni = 0; ni < 4; ++ni) \
      bfr[ni] = *(const bf16x8*)(Bb_ + (wc * 64 + ni * 16 + fr) * 32 + fko); \
  } while (0)

#define DS_AF(buf, kh, mh) do { \
    const short* Ab_ = (const short*)(smem + (buf) * 32768 + (kh) * 16384); \
    _Pragma("unroll") \
    for (int mi = 0; mi < 4; ++mi) \
      af[mi] = *(const bf16x8*)(Ab_ + (wr * 128 + ((mh) * 4 + mi) * 16 + fr) * 32 + fko); \
  } while (0)

  // swapped operands: acc[mi][ni] = C^T fragment
  // value(lane,reg) = C[row = mi*16+(lane&15)][col = ni*16+(lane>>4)*4+reg]
#define MFMA16(mh) do { \
    __builtin_amdgcn_s_setprio(1); \
    _Pragma("unroll") \
    for (int mi = 0; mi < 4; ++mi) \
      _Pragma("unroll") \
      for (int ni = 0; ni < 4; ++ni) \
        acc[(mh) * 4 + mi][ni] = __builtin_amdgcn_mfma_f32_16x16x32_bf16( \
            bfr[ni], af[mi], acc[(mh) * 4 + mi][ni], 0, 0, 0); \
    __builtin_amdgcn_s_setprio(0); \
  } while (0)

#define BAR() __builtin_amdgcn_s_barrier()
#define LGKM0() asm volatile("s_waitcnt lgkmcnt(0)" ::: "memory")
#define WCNT(s) asm volatile("s_waitcnt " s ::: "memory")

#define ITER(kk, DO_S0, DO_S2, V1, V3) do { \
    int b_ = (kk) & 1; \
    bf16x8 af[4], bfr[4]; \
    if (DO_S0) STAGE_HALF(((kk) + 1) & 1, (kk) + 1, 1); \
    DS_BFR(b_, 0); DS_AF(b_, 0, 0); \
    BAR(); LGKM0(); \
    MFMA16(0); \
    BAR(); \
    DS_AF(b_, 0, 1); \
    BAR(); LGKM0(); \
    MFMA16(1); \
    WCNT(V1); BAR(); \
    if (DO_S2) STAGE_HALF(b_, (kk) + 2, 0); \
    DS_BFR(b_, 1); DS_AF(b_, 1, 0); \
    BAR(); LGKM0(); \
    MFMA16(0); \
    BAR(); \
    DS_AF(b_, 1, 1); \
    BAR(); LGKM0(); \
    MFMA16(1); \
    WCNT(V3); BAR(); \
  } while (0)

  // prologue: kh0(0), kh1(0), kh0(1) in flight (12); retire kh0(0)
  STAGE_HALF(0, 0, 0);
  STAGE_HALF(0, 0, 1);
  STAGE_HALF(1, 1, 0);
  WCNT("vmcnt(8)");
  BAR();

  #pragma unroll 1
  for (int kt = 0; kt < 6; ++kt)
    ITER(kt, true, true, "vmcnt(8)", "vmcnt(8)");
  ITER(6, true, false, "vmcnt(8)", "vmcnt(4)");
  ITER(7, false, false, "vmcnt(0)", "vmcnt(0)");

  // ---- epilogue: bias + relu + csum; padded-LDS repack -> coalesced stores
  const int cr = lane & 15;            // output row within 16-frag
  const int cg = (lane >> 4) * 4;      // output col base within 16-frag
  float4 bias4[4];
  #pragma unroll
  for (int ni = 0; ni < 4; ++ni)
    bias4[ni] = *(const float4*)(b1 + bcol + wc * 64 + ni * 16 + cg);

  float cl[4][4];
  #pragma unroll
  for (int ni = 0; ni < 4; ++ni)
    #pragma unroll
    for (int r = 0; r < 4; ++r)
      cl[ni][r] = 0.f;

  short* pk = (short*)smem;            // [128][264] shorts = 67584 B (fits 128 KB)
  #pragma unroll 1
  for (int half = 0; half < 2; ++half) {
    __syncthreads();                   // K-loop reads / prev half's stores done
    if (wr == half) {                  // owning waves write their 128 rows
      #pragma unroll
      for (int mi = 0; mi < 8; ++mi) {
        int lrow = mi * 16 + cr;       // 0..127 within half
        #pragma unroll
        for (int ni = 0; ni < 4; ++ni) {
          float v0 = fmaxf(acc[mi][ni][0] + bias4[ni].x, 0.f);
          float v1 = fmaxf(acc[mi][ni][1] + bias4[ni].y, 0.f);
          float v2 = fmaxf(acc[mi][ni][2] + bias4[ni].z, 0.f);
          float v3 = fmaxf(acc[mi][ni][3] + bias4[ni].w, 0.f);
          cl[ni][0] += v0; cl[ni][1] += v1; cl[ni][2] += v2; cl[ni][3] += v3;
          short4 o;
          o.x = f2b(v0); o.y = f2b(v1); o.z = f2b(v2); o.w = f2b(v3);
          *(short4*)(pk + lrow * 264 + wc * 64 + ni * 16 + cg) = o;
        }
      }
    }
    __syncthreads();
    // all 8 waves store 64 KB: 128 rows x 512 B, fully coalesced b128
    #pragma unroll
    for (int i = 0; i < 8; ++i) {
      int c = tid + i * 512;           // 0..4095 chunks of 16 B
      int row = c >> 5, ch = c & 31;
      bf16x8 vv = *(const bf16x8*)(pk + row * 264 + ch * 8);
      *(bf16x8*)(Aout + (size_t)(brow + half * 128 + row) * HID + bcol + ch * 8) = vv;
    }
  }

  // column sums: reduce over the 16 rows (lanes sharing lane>>4)
  #pragma unroll
  for (int ni = 0; ni < 4; ++ni)
    #pragma unroll
    for (int r = 0; r < 4; ++r) {
      #pragma unroll
      for (int m = 1; m < 16; m <<= 1)
        cl[ni][r] += __shfl_xor(cl[ni][r], m);
    }
  if (cr == 0) {                       // 4 lanes/wave; wr=0/1 -> 2-way contention
    #pragma unroll
    for (int ni = 0; ni < 4; ++ni)
      #pragma unroll
      for (int r = 0; r < 4; ++r)
        atomicAdd(&csum[wc * 64 + ni * 16 + cg + r], cl[ni][r]);
  }
  __syncthreads();
  if (tid < 256) atomicAdd(&colsum[bcol + tid], csum[tid]);
}

// ---- K2/K5: vout[col] += sum_i vin[i] * W[i][col]  (W: [4096][4096] fp32) ----
__global__ __launch_bounds__(256) void k_gemv_at(const float* __restrict__ W,
                                                 const float* __restrict__ vin,
                                                 float* __restrict__ vout) {
  const int col = blockIdx.x * 1024 + threadIdx.x * 4;
  const int r0  = blockIdx.y * 64;
  float4 accv = {0.f, 0.f, 0.f, 0.f};
  const float* base = W + (size_t)r0 * HID + col;
  #pragma unroll 16
  for (int i = 0; i < 64; ++i) {
    float vi = vin[r0 + i];
    float4 wv = *(const float4*)(base + (size_t)i * HID);
    accv.x += vi * wv.x; accv.y += vi * wv.y;
    accv.z += vi * wv.z; accv.w += vi * wv.w;
  }
  atomicAdd(&vout[col + 0], accv.x);
  atomicAdd(&vout[col + 1], accv.y);
  atomicAdd(&vout[col + 2], accv.z);
  atomicAdd(&vout[col + 3], accv.w);
}

// ---- K3: t[row] = W2[row,:] . s ; extra block computes beta = b2 . s ----
__global__ __launch_bounds__(256) void k_gemv_row(const float* __restrict__ W,
                                                  const float* __restrict__ vin,
                                                  const float* __restrict__ b2,
                                                  float* __restrict__ vout,
                                                  float* __restrict__ beta) {
  __shared__ float red[4];
  if (blockIdx.x == HID / 4) {           // beta block
    float p = 0.f;
    for (int j = threadIdx.x; j < HID; j += 256) p += b2[j] * vin[j];
    #pragma unroll
    for (int o = 32; o > 0; o >>= 1) p += __shfl_down(p, o);
    int lane = threadIdx.x & 63, w = threadIdx.x >> 6;
    if (lane == 0) red[w] = p;
    __syncthreads();
    if (threadIdx.x == 0) beta[0] = red[0] + red[1] + red[2] + red[3];
    return;
  }
  int w = threadIdx.x >> 6, lane = threadIdx.x & 63;
  int row = blockIdx.x * 4 + w;
  const float* base = W + (size_t)row * HID;
  float p = 0.f;
  #pragma unroll 8
  for (int j = lane * 4; j < HID; j += 256) {
    float4 wv = *(const float4*)(base + j);
    float4 sv = *(const float4*)(vin + j);
    p += wv.x * sv.x + wv.y * sv.y + wv.z * sv.z + wv.w * sv.w;
  }
  #pragma unroll
  for (int o = 32; o > 0; o >>= 1) p += __shfl_down(p, o);
  if (lane == 0) vout[row] = p;
}

// ---- K4: kv[row] = A[row,:] . t + beta   (A bf16) ----
__global__ __launch_bounds__(256) void k_kv(const short* __restrict__ A,
                                            const float* __restrict__ t,
                                            const float* __restrict__ beta,
                                            float* __restrict__ kv) {
  int w = threadIdx.x >> 6, lane = threadIdx.x & 63;
  int row = blockIdx.x * 4 + w;
  const short* base = A + (size_t)row * HID;
  float p = 0.f;
  #pragma unroll
  for (int j = lane * 8; j < HID; j += 512) {
    bf16x8 av = *(const bf16x8*)(base + j);
    float4 t0 = *(const float4*)(t + j);
    float4 t1 = *(const float4*)(t + j + 4);
    p += b2f(av[0]) * t0.x + b2f(av[1]) * t0.y + b2f(av[2]) * t0.z + b2f(av[3]) * t0.w
       + b2f(av[4]) * t1.x + b2f(av[5]) * t1.y + b2f(av[6]) * t1.z + b2f(av[7]) * t1.w;
  }
  #pragma unroll
  for (int o = 32; o > 0; o >>= 1) p += __shfl_down(p, o);
  if (lane == 0) kv[row] = p + beta[0];
}

// ---- K6: out = relu(uacc) . W4 + b4 ----
__global__ __launch_bounds__(256) void k_final(const float* __restrict__ uacc,
                                               const float* __restrict__ W4,
                                               const float* __restrict__ b4,
                                               float* __restrict__ out) {
  __shared__ float red[4];
  float p = 0.f;
  for (int j = threadIdx.x; j < HID; j += 256) {
    float uv = uacc[j];
    uv = uv > 0.f ? uv : 0.f;
    p += uv * W4[j];
  }
  #pragma unroll
  for (int o = 32; o > 0; o >>= 1) p += __shfl_down(p, o);
  int lane = threadIdx.x & 63, w = threadIdx.x >> 6;
  if (lane == 0) red[w] = p;
  __syncthreads();
  if (threadIdx.x == 0) out[0] = red[0] + red[1] + red[2] + red[3] + b4[0];
}

extern "C" void kernel_launch(void* const* d_in, const int* in_sizes, int n_in,
                              void* d_out, int out_size, void* d_ws, size_t ws_size,
                              hipStream_t stream) {
  const float* x  = (const float*)d_in[0];
  // d_in[1] = edge_index (dead in the reference)
  const float* W1 = (const float*)d_in[2];
  const float* b1 = (const float*)d_in[3];
  const float* W2 = (const float*)d_in[4];
  const float* b2 = (const float*)d_in[5];
  const float* W3 = (const float*)d_in[6];
  const float* b3 = (const float*)d_in[7];
  const float* W4 = (const float*)d_in[8];
  const float* b4 = (const float*)d_in[9];
  float* out = (float*)d_out;

  char* ws = (char*)d_ws;
  short* Abf  = (short*)(ws);                 // 32 MB
  short* xb   = (short*)(ws + 33554432);      // 4 MB
  short* w1t  = (short*)(ws + 37748736);      // 4 MB
  float* aacc = (float*)(ws + 41943040);
  float* svec = (float*)(ws + 41959424);
  float* tvec = (float*)(ws + 41975808);
  float* kvv  = (float*)(ws + 41992192);
  float* uacc = (float*)(ws + 42008576);
  float* beta = (float*)(ws + 42024960);

  k_prep    <<<dim3(3088),     dim3(256), 0, stream>>>(x, W1, b2, b3, xb, w1t, aacc, svec, uacc);
  k_gemm1   <<<dim3(256),      dim3(512), 131072, stream>>>(xb, w1t, b1, Abf, aacc);
  k_gemv_at <<<dim3(4, 64),    dim3(256), 0, stream>>>(W2, aacc, svec);
  k_gemv_row<<<dim3(1025),     dim3(256), 0, stream>>>(W2, svec, b2, tvec, beta);
  k_kv      <<<dim3(1024),     dim3(256), 0, stream>>>(Abf, tvec, beta, kvv);
  k_gemv_at <<<dim3(4, 64),    dim3(256), 0, stream>>>(W3, kvv, uacc);
  k_final   <<<dim3(1),        dim3(256), 0, stream>>>(uacc, W4, b4, out);
}

// Round 16
// 85.747 us; speedup vs baseline: 3.3599x; 1.0715x over previous
//
#include <hip/hip_runtime.h>

#define NODES 4096
#define NDIM  512
#define HID   4096

typedef __attribute__((ext_vector_type(8))) short bf16x8;
typedef __attribute__((ext_vector_type(4))) float f32x4;

__device__ __forceinline__ float b2f(short v) {
  union { unsigned int u; float f; } c;
  c.u = ((unsigned int)(unsigned short)v) << 16;
  return c.f;
}
__device__ __forceinline__ short f2b(float f) {
  union { float f; unsigned int u; } c; c.f = f;
  unsigned int r = c.u + 0x7fffu + ((c.u >> 16) & 1u);  // round-nearest-even
  return (short)(r >> 16);
}

// ---- K0: fused prep: cast x->bf16 (16B stores) | transpose W1 | init accs ----
__global__ __launch_bounds__(256) void k_prep(const float* __restrict__ x,
                                              const float* __restrict__ W1,
                                              const float* __restrict__ b2,
                                              const float* __restrict__ b4,
                                              short* __restrict__ xb,
                                              short* __restrict__ w1t,
                                              float* __restrict__ aacc,
                                              float* __restrict__ svec,
                                              float* __restrict__ out) {
  __shared__ float tile[32][33];
  int b = blockIdx.x;
  if (b < 1024) {                       // cast x (4096x512 fp32 -> bf16), 8/thread
    int i = (b * 256 + threadIdx.x) * 8;
    float4 v0 = *(const float4*)(x + i);
    float4 v1 = *(const float4*)(x + i + 4);
    bf16x8 o;
    o[0] = f2b(v0.x); o[1] = f2b(v0.y); o[2] = f2b(v0.z); o[3] = f2b(v0.w);
    o[4] = f2b(v1.x); o[5] = f2b(v1.y); o[6] = f2b(v1.z); o[7] = f2b(v1.w);
    *(bf16x8*)(xb + i) = o;
  } else if (b < 3072) {                // transpose W1 [512][4096] -> [4096][512] bf16
    int t = b - 1024;
    int n0 = (t & 127) * 32;
    int k0 = (t >> 7) * 32;
    int tx = threadIdx.x & 31, ty = threadIdx.x >> 5;
    #pragma unroll
    for (int j = 0; j < 4; ++j) {
      int kk = ty + j * 8;
      tile[kk][tx] = W1[(size_t)(k0 + kk) * HID + n0 + tx];
    }
    __syncthreads();
    #pragma unroll
    for (int j = 0; j < 4; ++j) {
      int nn = ty + j * 8;
      w1t[(size_t)(n0 + nn) * NDIM + k0 + tx] = f2b(tile[tx][nn]);
    }
  } else {                              // init: a=0, s=N*b2, out=b4
    int j = (b - 3072) * 256 + threadIdx.x;
    aacc[j] = 0.0f;
    svec[j] = (float)NODES * b2[j];
    if (b == 3072 && threadIdx.x == 0) out[0] = b4[0];
  }
}

// ---- K1: A = relu(x @ W1 + b1) (bf16 MFMA), fused column sums ----
// 256x256 tile, BK=64, 8 waves (2M x 4N, 128x64/wave). 4-phase fine-interleave
// per K-tile: {ds_read || half-tile stage -> barrier -> lgkmcnt(0) -> 16 MFMA
// -> barrier}, counted vmcnt(8). Granule swizzle + padded-LDS repack epilogue.
__global__ __launch_bounds__(512, 2) void k_gemm1(const short* __restrict__ xb,
                                                  const short* __restrict__ w1t,
                                                  const float* __restrict__ b1,
                                                  short* __restrict__ Aout,
                                                  float* __restrict__ colsum) {
  extern __shared__ char smem[];        // 131072 B:
                                        // A: buf*32768 + kh*16384   (0..65535)
                                        // B: 65536 + buf*32768 + kh*16384
  __shared__ float csum[256];

  const int tid  = threadIdx.x;
  const int lane = tid & 63;
  const int wid  = tid >> 6;            // 0..7
  const int wr   = wid >> 2;            // 0..1  (M)
  const int wc   = wid & 3;             // 0..3  (N)

  // XCD-aware swizzle (256 blocks, %8==0 -> simple bijective form)
  int bswz = (blockIdx.x & 7) * 32 + (blockIdx.x >> 3);
  const int brow = (bswz >> 4) * 256, bcol = (bswz & 15) * 256;

  f32x4 acc[8][4];
  #pragma unroll
  for (int i = 0; i < 8; ++i)
    #pragma unroll
    for (int j = 0; j < 4; ++j)
      acc[i][j] = (f32x4){0.f, 0.f, 0.f, 0.f};

  if (tid < 256) csum[tid] = 0.f;

  const int fr = lane & 15;
  // swizzled fragment granule: logical g = lane>>4, row-phase = (fr>>1)&3
  const int fko = ((lane >> 4) ^ ((lane >> 1) & 3)) * 8;  // shorts, in [0,32)

  // staging: each kh-subtile is [256][32] shorts (64-B rows), LDS dest linear.
  // Source granule pre-swizzled with the SAME involution: g' = g ^ ((row>>1)&3).
  const int off0 = tid * 16;
  const int row0 = off0 >> 6;
  const int gs   = (off0 >> 4) & 3;                     // linear granule
  const int ce0  = (gs ^ ((row0 >> 1) & 3)) * 8;        // swizzled source offset
  const short* gA0 = xb  + (size_t)(brow + row0) * NDIM + ce0;
  const short* gA1 = xb  + (size_t)(brow + row0 + 128) * NDIM + ce0;
  const short* gB0 = w1t + (size_t)(bcol + row0) * NDIM + ce0;
  const short* gB1 = w1t + (size_t)(bcol + row0 + 128) * NDIM + ce0;

#define GLOAD(src, dst) __builtin_amdgcn_global_load_lds( \
    (const __attribute__((address_space(1))) void*)(src), \
    (__attribute__((address_space(3))) void*)(dst), 16, 0, 0)

#define STAGE_HALF(buf, tile_, kh) do { \
    char* bA_ = smem + (buf) * 32768 + (kh) * 16384; \
    char* bB_ = smem + 65536 + (buf) * 32768 + (kh) * 16384; \
    int ks_ = (tile_) * 64 + (kh) * 32; \
    GLOAD(gA0 + ks_, bA_ + off0); \
    GLOAD(gA1 + ks_, bA_ + off0 + 8192); \
    GLOAD(gB0 + ks_, bB_ + off0); \
    GLOAD(gB1 + ks_, bB_ + off0 + 8192); \
  } while (0)

#define DS_BFR(buf, kh) do { \
    const short* Bb_ = (const short*)(smem + 65536 + (buf) * 32768 + (kh) * 16384); \
    _Pragma("unroll") \
    for (int ni = 0; ni < 4; ++ni) \
      bfr[ni] = *(const bf16x8*)(Bb_ + (wc * 64 + ni * 16 + fr) * 32 + fko); \
  } while (0)

#define DS_AF(buf, kh, mh) do { \
    const short* Ab_ = (const short*)(smem + (buf) * 32768 + (kh) * 16384); \
    _Pragma("unroll") \
    for (int mi = 0; mi < 4; ++mi) \
      af[mi] = *(const bf16x8*)(Ab_ + (wr * 128 + ((mh) * 4 + mi) * 16 + fr) * 32 + fko); \
  } while (0)

  // swapped operands: acc[mi][ni] = C^T fragment
  // value(lane,reg) = C[row = mi*16+(lane&15)][col = ni*16+(lane>>4)*4+reg]
#define MFMA16(mh) do { \
    __builtin_amdgcn_s_setprio(1); \
    _Pragma("unroll") \
    for (int mi = 0; mi < 4; ++mi) \
      _Pragma("unroll") \
      for (int ni = 0; ni < 4; ++ni) \
        acc[(mh) * 4 + mi][ni] = __builtin_amdgcn_mfma_f32_16x16x32_bf16( \
            bfr[ni], af[mi], acc[(mh) * 4 + mi][ni], 0, 0, 0); \
    __builtin_amdgcn_s_setprio(0); \
  } while (0)

#define BAR() __builtin_amdgcn_s_barrier()
#define LGKM0() asm volatile("s_waitcnt lgkmcnt(0)" ::: "memory")
#define WCNT(s) asm volatile("s_waitcnt " s ::: "memory")

#define ITER(kk, DO_S0, DO_S2, V1, V3) do { \
    int b_ = (kk) & 1; \
    bf16x8 af[4], bfr[4]; \
    if (DO_S0) STAGE_HALF(((kk) + 1) & 1, (kk) + 1, 1); \
    DS_BFR(b_, 0); DS_AF(b_, 0, 0); \
    BAR(); LGKM0(); \
    MFMA16(0); \
    BAR(); \
    DS_AF(b_, 0, 1); \
    BAR(); LGKM0(); \
    MFMA16(1); \
    WCNT(V1); BAR(); \
    if (DO_S2) STAGE_HALF(b_, (kk) + 2, 0); \
    DS_BFR(b_, 1); DS_AF(b_, 1, 0); \
    BAR(); LGKM0(); \
    MFMA16(0); \
    BAR(); \
    DS_AF(b_, 1, 1); \
    BAR(); LGKM0(); \
    MFMA16(1); \
    WCNT(V3); BAR(); \
  } while (0)

  // prologue: kh0(0), kh1(0), kh0(1) in flight (12); retire kh0(0)
  STAGE_HALF(0, 0, 0);
  STAGE_HALF(0, 0, 1);
  STAGE_HALF(1, 1, 0);
  WCNT("vmcnt(8)");
  BAR();

  #pragma unroll 1
  for (int kt = 0; kt < 6; ++kt)
    ITER(kt, true, true, "vmcnt(8)", "vmcnt(8)");
  ITER(6, true, false, "vmcnt(8)", "vmcnt(4)");
  ITER(7, false, false, "vmcnt(0)", "vmcnt(0)");

  // ---- epilogue: bias + relu + csum; padded-LDS repack -> coalesced stores
  const int cr = lane & 15;            // output row within 16-frag
  const int cg = (lane >> 4) * 4;      // output col base within 16-frag
  float4 bias4[4];
  #pragma unroll
  for (int ni = 0; ni < 4; ++ni)
    bias4[ni] = *(const float4*)(b1 + bcol + wc * 64 + ni * 16 + cg);

  float cl[4][4];
  #pragma unroll
  for (int ni = 0; ni < 4; ++ni)
    #pragma unroll
    for (int r = 0; r < 4; ++r)
      cl[ni][r] = 0.f;

  short* pk = (short*)smem;            // [128][264] shorts = 67584 B (fits 128 KB)
  #pragma unroll 1
  for (int half = 0; half < 2; ++half) {
    __syncthreads();                   // K-loop reads / prev half's stores done
    if (wr == half) {                  // owning waves write their 128 rows
      #pragma unroll
      for (int mi = 0; mi < 8; ++mi) {
        int lrow = mi * 16 + cr;       // 0..127 within half
        #pragma unroll
        for (int ni = 0; ni < 4; ++ni) {
          float v0 = fmaxf(acc[mi][ni][0] + bias4[ni].x, 0.f);
          float v1 = fmaxf(acc[mi][ni][1] + bias4[ni].y, 0.f);
          float v2 = fmaxf(acc[mi][ni][2] + bias4[ni].z, 0.f);
          float v3 = fmaxf(acc[mi][ni][3] + bias4[ni].w, 0.f);
          cl[ni][0] += v0; cl[ni][1] += v1; cl[ni][2] += v2; cl[ni][3] += v3;
          short4 o;
          o.x = f2b(v0); o.y = f2b(v1); o.z = f2b(v2); o.w = f2b(v3);
          *(short4*)(pk + lrow * 264 + wc * 64 + ni * 16 + cg) = o;
        }
      }
    }
    __syncthreads();
    // all 8 waves store 64 KB: 128 rows x 512 B, fully coalesced b128
    #pragma unroll
    for (int i = 0; i < 8; ++i) {
      int c = tid + i * 512;           // 0..4095 chunks of 16 B
      int row = c >> 5, ch = c & 31;
      bf16x8 vv = *(const bf16x8*)(pk + row * 264 + ch * 8);
      *(bf16x8*)(Aout + (size_t)(brow + half * 128 + row) * HID + bcol + ch * 8) = vv;
    }
  }

  // column sums: reduce over the 16 rows (lanes sharing lane>>4)
  #pragma unroll
  for (int ni = 0; ni < 4; ++ni)
    #pragma unroll
    for (int r = 0; r < 4; ++r) {
      #pragma unroll
      for (int m = 1; m < 16; m <<= 1)
        cl[ni][r] += __shfl_xor(cl[ni][r], m);
    }
  if (cr == 0) {                       // 4 lanes/wave; wr=0/1 -> 2-way contention
    #pragma unroll
    for (int ni = 0; ni < 4; ++ni)
      #pragma unroll
      for (int r = 0; r < 4; ++r)
        atomicAdd(&csum[wc * 64 + ni * 16 + cg + r], cl[ni][r]);
  }
  __syncthreads();
  if (tid < 256) atomicAdd(&colsum[bcol + tid], csum[tid]);
}

// ---- K2: vout[col] += sum_i vin[i] * W[i][col]  (W: [4096][4096] fp32) ----
__global__ __launch_bounds__(256) void k_gemv_at(const float* __restrict__ W,
                                                 const float* __restrict__ vin,
                                                 float* __restrict__ vout) {
  const int col = blockIdx.x * 1024 + threadIdx.x * 4;
  const int r0  = blockIdx.y * 64;
  float4 accv = {0.f, 0.f, 0.f, 0.f};
  const float* base = W + (size_t)r0 * HID + col;
  #pragma unroll 16
  for (int i = 0; i < 64; ++i) {
    float vi = vin[r0 + i];
    float4 wv = *(const float4*)(base + (size_t)i * HID);
    accv.x += vi * wv.x; accv.y += vi * wv.y;
    accv.z += vi * wv.z; accv.w += vi * wv.w;
  }
  atomicAdd(&vout[col + 0], accv.x);
  atomicAdd(&vout[col + 1], accv.y);
  atomicAdd(&vout[col + 2], accv.z);
  atomicAdd(&vout[col + 3], accv.w);
}

// ---- K3: t[row] = W2[row,:] . s ; extra block computes beta = b2 . s ----
__global__ __launch_bounds__(256) void k_gemv_row(const float* __restrict__ W,
                                                  const float* __restrict__ vin,
                                                  const float* __restrict__ b2,
                                                  float* __restrict__ vout,
                                                  float* __restrict__ beta) {
  __shared__ float red[4];
  if (blockIdx.x == HID / 4) {           // beta block
    float p = 0.f;
    for (int j = threadIdx.x; j < HID; j += 256) p += b2[j] * vin[j];
    #pragma unroll
    for (int o = 32; o > 0; o >>= 1) p += __shfl_down(p, o);
    int lane = threadIdx.x & 63, w = threadIdx.x >> 6;
    if (lane == 0) red[w] = p;
    __syncthreads();
    if (threadIdx.x == 0) beta[0] = red[0] + red[1] + red[2] + red[3];
    return;
  }
  int w = threadIdx.x >> 6, lane = threadIdx.x & 63;
  int row = blockIdx.x * 4 + w;
  const float* base = W + (size_t)row * HID;
  float p = 0.f;
  #pragma unroll 8
  for (int j = lane * 4; j < HID; j += 256) {
    float4 wv = *(const float4*)(base + j);
    float4 sv = *(const float4*)(vin + j);
    p += wv.x * sv.x + wv.y * sv.y + wv.z * sv.z + wv.w * sv.w;
  }
  #pragma unroll
  for (int o = 32; o > 0; o >>= 1) p += __shfl_down(p, o);
  if (lane == 0) vout[row] = p;
}

// ---- K4: kv[row] = A[row,:] . t + beta   (A bf16) ----
__global__ __launch_bounds__(256) void k_kv(const short* __restrict__ A,
                                            const float* __restrict__ t,
                                            const float* __restrict__ beta,
                                            float* __restrict__ kv) {
  int w = threadIdx.x >> 6, lane = threadIdx.x & 63;
  int row = blockIdx.x * 4 + w;
  const short* base = A + (size_t)row * HID;
  float p = 0.f;
  #pragma unroll
  for (int j = lane * 8; j < HID; j += 512) {
    bf16x8 av = *(const bf16x8*)(base + j);
    float4 t0 = *(const float4*)(t + j);
    float4 t1 = *(const float4*)(t + j + 4);
    p += b2f(av[0]) * t0.x + b2f(av[1]) * t0.y + b2f(av[2]) * t0.z + b2f(av[3]) * t0.w
       + b2f(av[4]) * t1.x + b2f(av[5]) * t1.y + b2f(av[6]) * t1.z + b2f(av[7]) * t1.w;
  }
  #pragma unroll
  for (int o = 32; o > 0; o >>= 1) p += __shfl_down(p, o);
  if (lane == 0) kv[row] = p + beta[0];
}

// ---- K5: fused W3 pass + final: out += sum_c relu(b3[c] + sum_r kv[r]W3[r][c]) W4[c]
// 128 blocks x 512 threads; block owns 32 complete columns (16 row-groups x 256).
__global__ __launch_bounds__(512) void k_w3_final(const float* __restrict__ W3,
                                                  const float* __restrict__ kvv,
                                                  const float* __restrict__ b3,
                                                  const float* __restrict__ W4,
                                                  float* __restrict__ out) {
  __shared__ float part[512];
  const int t  = threadIdx.x;
  const int cl = t & 31;                 // col within block
  const int rg = t >> 5;                 // row-group 0..15
  const int c  = blockIdx.x * 32 + cl;
  const float* base = W3 + (size_t)rg * 256 * HID + c;
  const float* kb   = kvv + rg * 256;
  float p = 0.f;
  #pragma unroll 32
  for (int i = 0; i < 256; ++i)
    p += kb[i] * base[(size_t)i * HID];
  part[t] = p;
  __syncthreads();
  if (t < 32) {
    float u = b3[c];
    #pragma unroll
    for (int g = 0; g < 16; ++g) u += part[g * 32 + t];
    u = fmaxf(u, 0.f);
    float v = u * W4[c];
    #pragma unroll
    for (int o = 16; o > 0; o >>= 1) v += __shfl_down(v, o);
    if (t == 0) atomicAdd(out, v);
  }
}

extern "C" void kernel_launch(void* const* d_in, const int* in_sizes, int n_in,
                              void* d_out, int out_size, void* d_ws, size_t ws_size,
                              hipStream_t stream) {
  const float* x  = (const float*)d_in[0];
  // d_in[1] = edge_index (dead in the reference)
  const float* W1 = (const float*)d_in[2];
  const float* b1 = (const float*)d_in[3];
  const float* W2 = (const float*)d_in[4];
  const float* b2 = (const float*)d_in[5];
  const float* W3 = (const float*)d_in[6];
  const float* b3 = (const float*)d_in[7];
  const float* W4 = (const float*)d_in[8];
  const float* b4 = (const float*)d_in[9];
  float* out = (float*)d_out;

  char* ws = (char*)d_ws;
  short* Abf  = (short*)(ws);                 // 32 MB
  short* xb   = (short*)(ws + 33554432);      // 4 MB
  short* w1t  = (short*)(ws + 37748736);      // 4 MB
  float* aacc = (float*)(ws + 41943040);
  float* svec = (float*)(ws + 41959424);
  float* tvec = (float*)(ws + 41975808);
  float* kvv  = (float*)(ws + 41992192);
  float* beta = (float*)(ws + 42024960);

  k_prep    <<<dim3(3088),     dim3(256), 0, stream>>>(x, W1, b2, b4, xb, w1t, aacc, svec, out);
  k_gemm1   <<<dim3(256),      dim3(512), 131072, stream>>>(xb, w1t, b1, Abf, aacc);
  k_gemv_at <<<dim3(4, 64),    dim3(256), 0, stream>>>(W2, aacc, svec);
  k_gemv_row<<<dim3(1025),     dim3(256), 0, stream>>>(W2, svec, b2, tvec, beta);
  k_kv      <<<dim3(1024),     dim3(256), 0, stream>>>(Abf, tvec, beta, kvv);
  k_w3_final<<<dim3(128),      dim3(512), 0, stream>>>(W3, kvv, b3, W4, out);
}